// Round 1
// baseline (619.084 us; speedup 1.0000x reference)
//
#include <hip/hip_runtime.h>
#include <hip/hip_bf16.h>
#include <stdint.h>

#define B_ROWS 32768
#define DDIM 1024
#define KDIM 512

typedef short bf16x8 __attribute__((ext_vector_type(8)));
typedef float f32x4 __attribute__((ext_vector_type(4)));

__device__ __forceinline__ unsigned short f2bfu(float f) {
  __hip_bfloat16 h = __float2bfloat16(f);
  unsigned short u; __builtin_memcpy(&u, &h, 2); return u;
}
__device__ __forceinline__ float bfu2f(unsigned int u) {
  return __uint_as_float(u << 16);
}
__device__ __forceinline__ unsigned int pack2(float lo, float hi) {
  return (unsigned int)f2bfu(lo) | ((unsigned int)f2bfu(hi) << 16);
}

// ---------------- small utility kernels ----------------
__global__ void zero_f32(float* __restrict__ p, int n) {
  int i = blockIdx.x * blockDim.x + threadIdx.x;
  if (i < n) p[i] = 0.0f;
}

// f32 -> bf16, 8 elems/thread
__global__ void cvt_bf16(const float* __restrict__ in, __hip_bfloat16* __restrict__ out, int n8) {
  int i = blockIdx.x * blockDim.x + threadIdx.x;
  if (i >= n8) return;
  const float4* p = (const float4*)in + (size_t)i * 2;
  float4 v0 = p[0], v1 = p[1];
  uint4 o;
  o.x = pack2(v0.x, v0.y); o.y = pack2(v0.z, v0.w);
  o.z = pack2(v1.x, v1.y); o.w = pack2(v1.z, v1.w);
  ((uint4*)out)[i] = o;
}

// normalize each row of W_proto [512,512] -> bf16 Cn
__global__ __launch_bounds__(256) void cn_norm(const float* __restrict__ Wp,
                                               __hip_bfloat16* __restrict__ Cn) {
  const int row = blockIdx.x;
  const int t = threadIdx.x;
  const float* r = Wp + (size_t)row * KDIM;
  float v0 = r[t], v1 = r[t + 256];
  float ss = v0 * v0 + v1 * v1;
  #pragma unroll
  for (int m = 1; m < 64; m <<= 1) ss += __shfl_xor(ss, m);
  __shared__ float wsm[4];
  if ((t & 63) == 0) wsm[t >> 6] = ss;
  __syncthreads();
  float sc = rsqrtf(wsm[0] + wsm[1] + wsm[2] + wsm[3]);
  Cn[(size_t)row * KDIM + t] = __float2bfloat16(v0 * sc);
  Cn[(size_t)row * KDIM + t + 256] = __float2bfloat16(v1 * sc);
}

__global__ void recip_scale(const float* __restrict__ cs, float* __restrict__ a, float sc) {
  int i = blockIdx.x * 256 + threadIdx.x;
  if (i < KDIM) a[i] = sc / cs[i];
}

__global__ void finalize_k(const float* __restrict__ loss, float* __restrict__ out) {
  out[0] = -loss[0] * (1.0f / (float)B_ROWS);
}

// ---------------- GEMM: C = A[M,Kd] * Bm[N,Kd]^T, bf16 in, f32 accum ----------------
// MODE 0: store bf16 Z + atomic row sum-of-squares into auxv[M]
// MODE 1: store f32  C * rsqrt(rnorm[row])            (scores_s)
// MODE 2: store f32  exp(C*rsqrt(rnorm[row])*10 - 10) (E) + atomic colsum into auxv[N]
template <int MODE>
__global__ __launch_bounds__(256)
void gemm_bt(const __hip_bfloat16* __restrict__ A, const __hip_bfloat16* __restrict__ Bm,
             int Kd, void* __restrict__ outp, float* __restrict__ auxv,
             const float* __restrict__ rnorm) {
  __shared__ __hip_bfloat16 sA[128 * 64];
  __shared__ __hip_bfloat16 sB[128 * 64];
  const int tid = threadIdx.x;
  const int lane = tid & 63;
  const int wid = tid >> 6;
  const int wm = wid >> 1, wn = wid & 1;
  const int row0 = blockIdx.x * 128;
  const int col0 = blockIdx.y * 128;

  f32x4 acc[4][4] = {};

  const int nk = Kd >> 6;
  for (int kt = 0; kt < nk; ++kt) {
    const int k0 = kt << 6;
    // stage A tile [128 x 64] with XOR-swizzled source (LDS dest linear)
    #pragma unroll
    for (int i = 0; i < 4; ++i) {
      int L = i * 256 + tid;
      int r = L >> 3, sl = L & 7;
      int sg = sl ^ (r & 7);
      __builtin_amdgcn_global_load_lds(
          (__attribute__((address_space(1))) void*)(A + (size_t)(row0 + r) * Kd + k0 + sg * 8),
          (__attribute__((address_space(3))) void*)(sA + L * 8), 16, 0, 0);
    }
    #pragma unroll
    for (int i = 0; i < 4; ++i) {
      int L = i * 256 + tid;
      int r = L >> 3, sl = L & 7;
      int sg = sl ^ (r & 7);
      __builtin_amdgcn_global_load_lds(
          (__attribute__((address_space(1))) void*)(Bm + (size_t)(col0 + r) * Kd + k0 + sg * 8),
          (__attribute__((address_space(3))) void*)(sB + L * 8), 16, 0, 0);
    }
    __syncthreads();

    bf16x8 af[4][2], bfr[4][2];
    #pragma unroll
    for (int f = 0; f < 4; ++f) {
      #pragma unroll
      for (int kk = 0; kk < 2; ++kk) {
        int ra = wm * 64 + f * 16 + (lane & 15);
        int rb = wn * 64 + f * 16 + (lane & 15);
        int sl = kk * 4 + (lane >> 4);
        af[f][kk]  = *(const bf16x8*)(sA + ra * 64 + (sl ^ (ra & 7)) * 8);
        bfr[f][kk] = *(const bf16x8*)(sB + rb * 64 + (sl ^ (rb & 7)) * 8);
      }
    }
    #pragma unroll
    for (int kk = 0; kk < 2; ++kk)
      #pragma unroll
      for (int fm = 0; fm < 4; ++fm)
        #pragma unroll
        for (int fn = 0; fn < 4; ++fn)
          acc[fm][fn] = __builtin_amdgcn_mfma_f32_16x16x32_bf16(af[fm][kk], bfr[fn][kk],
                                                                acc[fm][fn], 0, 0, 0);
    __syncthreads();
  }

  const int r0 = row0 + wm * 64;
  const int c0w = col0 + wn * 64;
  if constexpr (MODE == 0) {
    __hip_bfloat16* Z = (__hip_bfloat16*)outp;
    #pragma unroll
    for (int fm = 0; fm < 4; ++fm) {
      #pragma unroll
      for (int j = 0; j < 4; ++j) {
        const int row = r0 + fm * 16 + ((lane >> 4) << 2) + j;
        float ssq = 0.0f;
        #pragma unroll
        for (int fn = 0; fn < 4; ++fn) {
          float v = acc[fm][fn][j];
          Z[(size_t)row * KDIM + c0w + fn * 16 + (lane & 15)] = __float2bfloat16(v);
          ssq += v * v;
        }
        ssq += __shfl_xor(ssq, 1); ssq += __shfl_xor(ssq, 2);
        ssq += __shfl_xor(ssq, 4); ssq += __shfl_xor(ssq, 8);
        if ((lane & 15) == 0) atomicAdd(&auxv[row], ssq);
      }
    }
  } else if constexpr (MODE == 1) {
    float* C = (float*)outp;
    #pragma unroll
    for (int fm = 0; fm < 4; ++fm)
      #pragma unroll
      for (int j = 0; j < 4; ++j) {
        const int row = r0 + fm * 16 + ((lane >> 4) << 2) + j;
        const float sc = rsqrtf(rnorm[row]);
        #pragma unroll
        for (int fn = 0; fn < 4; ++fn)
          C[(size_t)row * KDIM + c0w + fn * 16 + (lane & 15)] = acc[fm][fn][j] * sc;
      }
  } else {
    float* Eo = (float*)outp;
    float colacc[4] = {0.f, 0.f, 0.f, 0.f};
    #pragma unroll
    for (int fm = 0; fm < 4; ++fm)
      #pragma unroll
      for (int j = 0; j < 4; ++j) {
        const int row = r0 + fm * 16 + ((lane >> 4) << 2) + j;
        const float sc = rsqrtf(rnorm[row]);
        #pragma unroll
        for (int fn = 0; fn < 4; ++fn) {
          float e = __expf(acc[fm][fn][j] * sc * 10.0f - 10.0f);
          Eo[(size_t)row * KDIM + c0w + fn * 16 + (lane & 15)] = e;
          colacc[fn] += e;
        }
      }
    #pragma unroll
    for (int fn = 0; fn < 4; ++fn) {
      float v = colacc[fn];
      v += __shfl_xor(v, 16); v += __shfl_xor(v, 32);
      if (lane < 16) atomicAdd(&auxv[c0w + fn * 16 + lane], v);
    }
  }
}

// ---------------- Sinkhorn passes ----------------
// per row j: dot = sum_k E[j,k]*a[k]; b = (1/B)/dot; colacc[k] += E[j,k]*b
__global__ __launch_bounds__(256)
void sink_iter(const float* __restrict__ E, const float* __restrict__ a,
               float* __restrict__ cs_out) {
  const int tid = threadIdx.x;
  const int lane = tid & 63;
  const int wid = tid >> 6;
  const int gw = blockIdx.x * 4 + wid;
  const int c0 = lane * 8;
  float4 a0 = *(const float4*)(a + c0);
  float4 a1 = *(const float4*)(a + c0 + 4);
  float ca[8] = {0, 0, 0, 0, 0, 0, 0, 0};
  const float cconst = 1.0f / (float)B_ROWS;
  #pragma unroll
  for (int rr = 0; rr < 8; ++rr) {
    const size_t j = (size_t)gw * 8 + rr;
    const float* row = E + j * KDIM + c0;
    float4 e0 = *(const float4*)(row);
    float4 e1 = *(const float4*)(row + 4);
    float dot = e0.x * a0.x + e0.y * a0.y + e0.z * a0.z + e0.w * a0.w
              + e1.x * a1.x + e1.y * a1.y + e1.z * a1.z + e1.w * a1.w;
    #pragma unroll
    for (int m = 1; m < 64; m <<= 1) dot += __shfl_xor(dot, m);
    float b = cconst / dot;
    ca[0] += e0.x * b; ca[1] += e0.y * b; ca[2] += e0.z * b; ca[3] += e0.w * b;
    ca[4] += e1.x * b; ca[5] += e1.y * b; ca[6] += e1.z * b; ca[7] += e1.w * b;
  }
  __shared__ float csl[4 * KDIM];
  #pragma unroll
  for (int e = 0; e < 8; ++e) csl[wid * KDIM + c0 + e] = ca[e];
  __syncthreads();
  float s0 = csl[tid] + csl[KDIM + tid] + csl[2 * KDIM + tid] + csl[3 * KDIM + tid];
  float s1 = csl[tid + 256] + csl[KDIM + tid + 256] + csl[2 * KDIM + tid + 256] + csl[3 * KDIM + tid + 256];
  atomicAdd(&cs_out[tid], s0);
  atomicAdd(&cs_out[tid + 256], s1);
}

// final: q = E*a/rowdot; logp = x - max - lse (x = scores_s*10); loss += sum q*logp
__global__ __launch_bounds__(256)
void sink_final(const float* __restrict__ E, const float* __restrict__ a,
                const float* __restrict__ S, float* __restrict__ loss) {
  const int tid = threadIdx.x;
  const int lane = tid & 63;
  const int wid = tid >> 6;
  const int gw = blockIdx.x * 4 + wid;
  const int c0 = lane * 8;
  float4 a0 = *(const float4*)(a + c0);
  float4 a1 = *(const float4*)(a + c0 + 4);
  float av[8] = {a0.x, a0.y, a0.z, a0.w, a1.x, a1.y, a1.z, a1.w};
  float wsum = 0.0f;
  for (int rr = 0; rr < 8; ++rr) {
    const size_t j = (size_t)gw * 8 + rr;
    const float* erow = E + j * KDIM + c0;
    const float* srow = S + j * KDIM + c0;
    float4 e0 = *(const float4*)(erow);
    float4 e1 = *(const float4*)(erow + 4);
    float4 s0 = *(const float4*)(srow);
    float4 s1 = *(const float4*)(srow + 4);
    float ev[8] = {e0.x, e0.y, e0.z, e0.w, e1.x, e1.y, e1.z, e1.w};
    float xv[8] = {s0.x * 10.f, s0.y * 10.f, s0.z * 10.f, s0.w * 10.f,
                   s1.x * 10.f, s1.y * 10.f, s1.z * 10.f, s1.w * 10.f};
    float dot = 0.f, mx = -1e30f;
    #pragma unroll
    for (int e = 0; e < 8; ++e) { dot += ev[e] * av[e]; mx = fmaxf(mx, xv[e]); }
    #pragma unroll
    for (int m = 1; m < 64; m <<= 1) dot += __shfl_xor(dot, m);
    #pragma unroll
    for (int m = 1; m < 64; m <<= 1) mx = fmaxf(mx, __shfl_xor(mx, m));
    float se = 0.f;
    #pragma unroll
    for (int e = 0; e < 8; ++e) se += __expf(xv[e] - mx);
    #pragma unroll
    for (int m = 1; m < 64; m <<= 1) se += __shfl_xor(se, m);
    float lse = __logf(se);
    float part = 0.f;
    #pragma unroll
    for (int e = 0; e < 8; ++e) part += ev[e] * av[e] * (xv[e] - mx - lse);
    wsum += part / dot;
  }
  #pragma unroll
  for (int m = 1; m < 64; m <<= 1) wsum += __shfl_xor(wsum, m);
  if (lane == 0) atomicAdd(loss, wsum);
}

// ---------------- launcher ----------------
extern "C" void kernel_launch(void* const* d_in, const int* in_sizes, int n_in,
                              void* d_out, int out_size, void* d_ws, size_t ws_size,
                              hipStream_t stream) {
  const float* s  = (const float*)d_in[0];
  const float* t  = (const float*)d_in[1];
  const float* Wn = (const float*)d_in[2];
  const float* Wp = (const float*)d_in[3];
  float* out = (float*)d_out;

  char* w = (char*)d_ws;
  __hip_bfloat16* sbf = (__hip_bfloat16*)w; w += (size_t)B_ROWS * DDIM * 2;   // 64 MB (s then t)
  __hip_bfloat16* wnb = (__hip_bfloat16*)w; w += (size_t)KDIM * DDIM * 2;     // 1 MB
  __hip_bfloat16* cnb = (__hip_bfloat16*)w; w += (size_t)KDIM * KDIM * 2;     // 0.5 MB
  __hip_bfloat16* zbf = (__hip_bfloat16*)w; w += (size_t)B_ROWS * KDIM * 2;   // 32 MB (Zs then Zt)
  float* ssc  = (float*)w;                  w += (size_t)B_ROWS * KDIM * 4;   // 64 MB scores_s
  float* ebuf = (float*)w;                  w += (size_t)B_ROWS * KDIM * 4;   // 64 MB E
  float* small = (float*)w;
  float* csA = small;
  float* csB = small + 512;
  float* csC = small + 1024;
  float* av  = small + 1536;
  float* lossac = small + 2048;
  float* rss_s = small + 2064;
  float* rss_t = rss_s + B_ROWS;
  const int nsmall = 2064 + 2 * B_ROWS;

  zero_f32<<<(nsmall + 255) / 256, 256, 0, stream>>>(small, nsmall);
  cvt_bf16<<<(KDIM * DDIM / 8 + 255) / 256, 256, 0, stream>>>(Wn, wnb, KDIM * DDIM / 8);
  cn_norm<<<KDIM, 256, 0, stream>>>(Wp, cnb);

  dim3 g1(B_ROWS / 128, KDIM / 128);
  // student branch
  cvt_bf16<<<(B_ROWS * DDIM / 8 + 255) / 256, 256, 0, stream>>>(s, sbf, B_ROWS * DDIM / 8);
  gemm_bt<0><<<g1, 256, 0, stream>>>(sbf, wnb, DDIM, zbf, rss_s, nullptr);
  gemm_bt<1><<<g1, 256, 0, stream>>>(zbf, cnb, KDIM, ssc, nullptr, rss_s);
  // teacher branch
  cvt_bf16<<<(B_ROWS * DDIM / 8 + 255) / 256, 256, 0, stream>>>(t, sbf, B_ROWS * DDIM / 8);
  gemm_bt<0><<<g1, 256, 0, stream>>>(sbf, wnb, DDIM, zbf, rss_t, nullptr);
  gemm_bt<2><<<g1, 256, 0, stream>>>(zbf, cnb, KDIM, ebuf, csA, rss_t);

  const float rK = 1.0f / (float)KDIM;
  recip_scale<<<2, 256, 0, stream>>>(csA, av, rK);
  sink_iter<<<B_ROWS / 32, 256, 0, stream>>>(ebuf, av, csB);
  recip_scale<<<2, 256, 0, stream>>>(csB, av, rK);
  sink_iter<<<B_ROWS / 32, 256, 0, stream>>>(ebuf, av, csC);
  recip_scale<<<2, 256, 0, stream>>>(csC, av, rK);
  sink_final<<<B_ROWS / 32, 256, 0, stream>>>(ebuf, av, ssc, lossac);
  finalize_k<<<1, 1, 0, stream>>>(lossac, out);
}

// Round 2
// 455.075 us; speedup vs baseline: 1.3604x; 1.3604x over previous
//
#include <hip/hip_runtime.h>
#include <hip/hip_bf16.h>
#include <stdint.h>

#define B_ROWS 32768
#define DDIM 1024
#define KDIM 512

typedef short bf16x8 __attribute__((ext_vector_type(8)));
typedef float f32x4 __attribute__((ext_vector_type(4)));

#define AS1 __attribute__((address_space(1)))
#define AS3 __attribute__((address_space(3)))

__device__ __forceinline__ unsigned short f2bfu(float f) {
  __hip_bfloat16 h = __float2bfloat16(f);
  unsigned short u; __builtin_memcpy(&u, &h, 2); return u;
}
__device__ __forceinline__ float bfu2f(unsigned int u) {
  return __uint_as_float(u << 16);
}
__device__ __forceinline__ unsigned int pack2(float lo, float hi) {
  return (unsigned int)f2bfu(lo) | ((unsigned int)f2bfu(hi) << 16);
}
__device__ __forceinline__ void bf8_to_f32(uint4 u, float* o) {
  o[0] = bfu2f(u.x & 0xffffu); o[1] = bfu2f(u.x >> 16);
  o[2] = bfu2f(u.y & 0xffffu); o[3] = bfu2f(u.y >> 16);
  o[4] = bfu2f(u.z & 0xffffu); o[5] = bfu2f(u.z >> 16);
  o[6] = bfu2f(u.w & 0xffffu); o[7] = bfu2f(u.w >> 16);
}

// ---------------- small utility kernels ----------------
__global__ void zero_small(float* __restrict__ p, int n, float* __restrict__ out) {
  int i = blockIdx.x * blockDim.x + threadIdx.x;
  if (i < n) p[i] = 0.0f;
  if (i == 0) out[0] = 0.0f;
}

// f32 -> bf16, 8 elems/thread (used for W_net only, 1 MB)
__global__ void cvt_bf16(const float* __restrict__ in, __hip_bfloat16* __restrict__ out, int n8) {
  int i = blockIdx.x * blockDim.x + threadIdx.x;
  if (i >= n8) return;
  const float4* p = (const float4*)in + (size_t)i * 2;
  float4 v0 = p[0], v1 = p[1];
  uint4 o;
  o.x = pack2(v0.x, v0.y); o.y = pack2(v0.z, v0.w);
  o.z = pack2(v1.x, v1.y); o.w = pack2(v1.z, v1.w);
  ((uint4*)out)[i] = o;
}

// normalize each row of W_proto [512,512] -> bf16 Cn
__global__ __launch_bounds__(256) void cn_norm(const float* __restrict__ Wp,
                                               __hip_bfloat16* __restrict__ Cn) {
  const int row = blockIdx.x;
  const int t = threadIdx.x;
  const float* r = Wp + (size_t)row * KDIM;
  float v0 = r[t], v1 = r[t + 256];
  float ss = v0 * v0 + v1 * v1;
  #pragma unroll
  for (int m = 1; m < 64; m <<= 1) ss += __shfl_xor(ss, m);
  __shared__ float wsm[4];
  if ((t & 63) == 0) wsm[t >> 6] = ss;
  __syncthreads();
  float sc = rsqrtf(wsm[0] + wsm[1] + wsm[2] + wsm[3]);
  Cn[(size_t)row * KDIM + t] = __float2bfloat16(v0 * sc);
  Cn[(size_t)row * KDIM + t + 256] = __float2bfloat16(v1 * sc);
}

// ---------------- GEMM1: Zn = l2norm_rows(A_f32[M,1024] @ Wn_bf16[512,1024]^T) ----------------
// BM=128, BN=512(full), BK=64, 512 threads (8 waves, 2m x 4n), wave tile 64x128.
__global__ __launch_bounds__(512, 2)
void gemm_ns(const float* __restrict__ A, const __hip_bfloat16* __restrict__ Bm,
             __hip_bfloat16* __restrict__ Z) {
  __shared__ __align__(16) __hip_bfloat16 sA[128 * 64];
  __shared__ __align__(16) __hip_bfloat16 sB[512 * 64];
  __shared__ float red[4][128];
  const int tid = threadIdx.x;
  const int lane = tid & 63;
  const int wid = tid >> 6;
  const int wm = wid >> 2, wn = wid & 3;
  const int row0 = blockIdx.x * 128;
  const int Kd = DDIM;

  f32x4 acc[4][8] = {};

  // A staging geometry: thread -> (row ar, quarter aq of 16 f32)
  const int ar = tid >> 2;
  const int aq = tid & 3;
  const float* agp = A + (size_t)(row0 + ar) * Kd + aq * 16;
  const int asl0 = (aq * 2) ^ (ar & 7);
  const int asl1 = (aq * 2 + 1) ^ (ar & 7);

  for (int kt = 0; kt < DDIM / 64; ++kt) {
    const int k0 = kt * 64;
    // stage B [512 x 64] bf16 via global_load_lds, source pre-swizzled
    #pragma unroll
    for (int i = 0; i < 8; ++i) {
      int L = i * 512 + tid;
      int r = L >> 3, sl = L & 7;
      __builtin_amdgcn_global_load_lds(
          (AS1 void*)(Bm + (size_t)r * Kd + k0 + ((sl ^ (r & 7)) << 3)),
          (AS3 void*)(sB + L * 8), 16, 0, 0);
    }
    // stage A [128 x 64]: f32 load -> bf16 -> swizzled ds_write
    float4 f0 = *(const float4*)(agp + k0);
    float4 f1 = *(const float4*)(agp + k0 + 4);
    float4 f2 = *(const float4*)(agp + k0 + 8);
    float4 f3 = *(const float4*)(agp + k0 + 12);
    uint4 w0, w1;
    w0.x = pack2(f0.x, f0.y); w0.y = pack2(f0.z, f0.w);
    w0.z = pack2(f1.x, f1.y); w0.w = pack2(f1.z, f1.w);
    w1.x = pack2(f2.x, f2.y); w1.y = pack2(f2.z, f2.w);
    w1.z = pack2(f3.x, f3.y); w1.w = pack2(f3.z, f3.w);
    *(uint4*)(sA + ar * 64 + asl0 * 8) = w0;
    *(uint4*)(sA + ar * 64 + asl1 * 8) = w1;
    __syncthreads();

    #pragma unroll
    for (int kk = 0; kk < 2; ++kk) {
      const int sl = kk * 4 + (lane >> 4);
      bf16x8 af[4], bfr[8];
      #pragma unroll
      for (int f = 0; f < 4; ++f) {
        int ra = wm * 64 + f * 16 + (lane & 15);
        af[f] = *(const bf16x8*)(sA + ra * 64 + ((sl ^ (ra & 7)) << 3));
      }
      #pragma unroll
      for (int f = 0; f < 8; ++f) {
        int rb = wn * 128 + f * 16 + (lane & 15);
        bfr[f] = *(const bf16x8*)(sB + rb * 64 + ((sl ^ (rb & 7)) << 3));
      }
      #pragma unroll
      for (int fm = 0; fm < 4; ++fm)
        #pragma unroll
        for (int fn = 0; fn < 8; ++fn)
          acc[fm][fn] = __builtin_amdgcn_mfma_f32_16x16x32_bf16(af[fm], bfr[fn],
                                                                acc[fm][fn], 0, 0, 0);
    }
    __syncthreads();
  }

  // epilogue: row ssq (in-block, cross-wave), then store normalized bf16
  #pragma unroll
  for (int fm = 0; fm < 4; ++fm)
    #pragma unroll
    for (int j = 0; j < 4; ++j) {
      float ssq = 0.0f;
      #pragma unroll
      for (int fn = 0; fn < 8; ++fn) { float v = acc[fm][fn][j]; ssq += v * v; }
      ssq += __shfl_xor(ssq, 1); ssq += __shfl_xor(ssq, 2);
      ssq += __shfl_xor(ssq, 4); ssq += __shfl_xor(ssq, 8);
      int rl = wm * 64 + fm * 16 + ((lane >> 4) << 2) + j;
      if ((lane & 15) == 0) red[wn][rl] = ssq;
    }
  __syncthreads();
  #pragma unroll
  for (int fm = 0; fm < 4; ++fm)
    #pragma unroll
    for (int j = 0; j < 4; ++j) {
      int rl = wm * 64 + fm * 16 + ((lane >> 4) << 2) + j;
      float sc = rsqrtf(red[0][rl] + red[1][rl] + red[2][rl] + red[3][rl]);
      const size_t row = row0 + rl;
      #pragma unroll
      for (int fn = 0; fn < 8; ++fn)
        Z[row * KDIM + wn * 128 + fn * 16 + (lane & 15)] =
            __float2bfloat16(acc[fm][fn][j] * sc);
    }
}

// ---------------- GEMM2: scores = Zn[M,512] @ Cn[512,512]^T ----------------
// MODE 0 (student): logp = x - log(sum exp x), x = scores*10, store bf16
// MODE 1 (teacher): E = exp(x - 10), store bf16 + colsum atomics
template <int MODE>
__global__ __launch_bounds__(512, 2)
void gemm_sc(const __hip_bfloat16* __restrict__ A, const __hip_bfloat16* __restrict__ Bm,
             __hip_bfloat16* __restrict__ outp, float* __restrict__ cs) {
  __shared__ __align__(16) __hip_bfloat16 sA[128 * 64];
  __shared__ __align__(16) __hip_bfloat16 sB[512 * 64];
  const int tid = threadIdx.x;
  const int lane = tid & 63;
  const int wid = tid >> 6;
  const int wm = wid >> 2, wn = wid & 3;
  const int row0 = blockIdx.x * 128;
  const int Kd = KDIM;

  f32x4 acc[4][8] = {};

  for (int kt = 0; kt < KDIM / 64; ++kt) {
    const int k0 = kt * 64;
    #pragma unroll
    for (int i = 0; i < 8; ++i) {
      int L = i * 512 + tid;
      int r = L >> 3, sl = L & 7;
      __builtin_amdgcn_global_load_lds(
          (AS1 void*)(Bm + (size_t)r * Kd + k0 + ((sl ^ (r & 7)) << 3)),
          (AS3 void*)(sB + L * 8), 16, 0, 0);
    }
    #pragma unroll
    for (int i = 0; i < 2; ++i) {
      int L = i * 512 + tid;
      int r = L >> 3, sl = L & 7;
      __builtin_amdgcn_global_load_lds(
          (AS1 void*)(A + (size_t)(row0 + r) * Kd + k0 + ((sl ^ (r & 7)) << 3)),
          (AS3 void*)(sA + L * 8), 16, 0, 0);
    }
    __syncthreads();

    #pragma unroll
    for (int kk = 0; kk < 2; ++kk) {
      const int sl = kk * 4 + (lane >> 4);
      bf16x8 af[4], bfr[8];
      #pragma unroll
      for (int f = 0; f < 4; ++f) {
        int ra = wm * 64 + f * 16 + (lane & 15);
        af[f] = *(const bf16x8*)(sA + ra * 64 + ((sl ^ (ra & 7)) << 3));
      }
      #pragma unroll
      for (int f = 0; f < 8; ++f) {
        int rb = wn * 128 + f * 16 + (lane & 15);
        bfr[f] = *(const bf16x8*)(sB + rb * 64 + ((sl ^ (rb & 7)) << 3));
      }
      #pragma unroll
      for (int fm = 0; fm < 4; ++fm)
        #pragma unroll
        for (int fn = 0; fn < 8; ++fn)
          acc[fm][fn] = __builtin_amdgcn_mfma_f32_16x16x32_bf16(af[fm], bfr[fn],
                                                                acc[fm][fn], 0, 0, 0);
    }
    __syncthreads();
  }

  if constexpr (MODE == 0) {
    __shared__ float red[4][128];
    #pragma unroll
    for (int fm = 0; fm < 4; ++fm)
      #pragma unroll
      for (int j = 0; j < 4; ++j) {
        float se = 0.0f;
        #pragma unroll
        for (int fn = 0; fn < 8; ++fn) se += __expf(acc[fm][fn][j] * 10.0f);
        se += __shfl_xor(se, 1); se += __shfl_xor(se, 2);
        se += __shfl_xor(se, 4); se += __shfl_xor(se, 8);
        int rl = wm * 64 + fm * 16 + ((lane >> 4) << 2) + j;
        if ((lane & 15) == 0) red[wn][rl] = se;
      }
    __syncthreads();
    #pragma unroll
    for (int fm = 0; fm < 4; ++fm)
      #pragma unroll
      for (int j = 0; j < 4; ++j) {
        int rl = wm * 64 + fm * 16 + ((lane >> 4) << 2) + j;
        float l = __logf(red[0][rl] + red[1][rl] + red[2][rl] + red[3][rl]);
        const size_t row = row0 + rl;
        #pragma unroll
        for (int fn = 0; fn < 8; ++fn)
          outp[row * KDIM + wn * 128 + fn * 16 + (lane & 15)] =
              __float2bfloat16(acc[fm][fn][j] * 10.0f - l);
      }
  } else {
    __shared__ float redc[2][512];
    float ca[8] = {0, 0, 0, 0, 0, 0, 0, 0};
    #pragma unroll
    for (int fm = 0; fm < 4; ++fm)
      #pragma unroll
      for (int j = 0; j < 4; ++j) {
        int rl = wm * 64 + fm * 16 + ((lane >> 4) << 2) + j;
        const size_t row = row0 + rl;
        #pragma unroll
        for (int fn = 0; fn < 8; ++fn) {
          float e = __expf(acc[fm][fn][j] * 10.0f - 10.0f);
          outp[row * KDIM + wn * 128 + fn * 16 + (lane & 15)] = __float2bfloat16(e);
          ca[fn] += e;
        }
      }
    #pragma unroll
    for (int fn = 0; fn < 8; ++fn) {
      float v = ca[fn];
      v += __shfl_xor(v, 16); v += __shfl_xor(v, 32);
      if (lane < 16) redc[wm][wn * 128 + fn * 16 + lane] = v;
    }
    __syncthreads();
    if (tid < 512) atomicAdd(&cs[tid], redc[0][tid] + redc[1][tid]);
  }
}

// ---------------- Sinkhorn passes (bf16 E) ----------------
// a[k] = (1/K)/cs_in[k]; per row: dot = sum E*a; b = (1/B)/dot; cs_out[k] += E*b
__global__ __launch_bounds__(256)
void sink_iter(const __hip_bfloat16* __restrict__ E, const float* __restrict__ cs_in,
               float* __restrict__ cs_out) {
  const int tid = threadIdx.x;
  const int lane = tid & 63;
  const int wid = tid >> 6;
  const int gw = blockIdx.x * 4 + wid;   // 512 blocks * 4 waves, 16 rows/wave
  const int c0 = lane * 8;
  float a[8];
  {
    float4 c1 = *(const float4*)(cs_in + c0);
    float4 c2 = *(const float4*)(cs_in + c0 + 4);
    const float rK = 1.0f / (float)KDIM;
    a[0] = rK / c1.x; a[1] = rK / c1.y; a[2] = rK / c1.z; a[3] = rK / c1.w;
    a[4] = rK / c2.x; a[5] = rK / c2.y; a[6] = rK / c2.z; a[7] = rK / c2.w;
  }
  float ca[8] = {0, 0, 0, 0, 0, 0, 0, 0};
  const float cB = 1.0f / (float)B_ROWS;
  for (int rr = 0; rr < 16; ++rr) {
    const size_t j = (size_t)gw * 16 + rr;
    uint4 u = *(const uint4*)(E + j * KDIM + c0);
    float e[8]; bf8_to_f32(u, e);
    float dot = 0.0f;
    #pragma unroll
    for (int q = 0; q < 8; ++q) dot += e[q] * a[q];
    #pragma unroll
    for (int m = 1; m < 64; m <<= 1) dot += __shfl_xor(dot, m);
    float b = cB / dot;
    #pragma unroll
    for (int q = 0; q < 8; ++q) ca[q] += e[q] * b;
  }
  __shared__ float csl[4][512];
  #pragma unroll
  for (int q = 0; q < 8; ++q) csl[wid][c0 + q] = ca[q];
  __syncthreads();
  float s0 = csl[0][tid] + csl[1][tid] + csl[2][tid] + csl[3][tid];
  float s1 = csl[0][tid + 256] + csl[1][tid + 256] + csl[2][tid + 256] + csl[3][tid + 256];
  atomicAdd(&cs_out[tid], s0);
  atomicAdd(&cs_out[tid + 256], s1);
}

// final: q = E*a/dot; loss -= (1/B) * sum q*logp  (accumulated into out[0])
__global__ __launch_bounds__(256)
void sink_final(const __hip_bfloat16* __restrict__ E, const float* __restrict__ cs_in,
                const __hip_bfloat16* __restrict__ L, float* __restrict__ out) {
  const int tid = threadIdx.x;
  const int lane = tid & 63;
  const int wid = tid >> 6;
  const int gw = blockIdx.x * 4 + wid;
  const int c0 = lane * 8;
  float a[8];
  {
    float4 c1 = *(const float4*)(cs_in + c0);
    float4 c2 = *(const float4*)(cs_in + c0 + 4);
    const float rK = 1.0f / (float)KDIM;
    a[0] = rK / c1.x; a[1] = rK / c1.y; a[2] = rK / c1.z; a[3] = rK / c1.w;
    a[4] = rK / c2.x; a[5] = rK / c2.y; a[6] = rK / c2.z; a[7] = rK / c2.w;
  }
  float wsum = 0.0f;
  for (int rr = 0; rr < 16; ++rr) {
    const size_t j = (size_t)gw * 16 + rr;
    uint4 ue = *(const uint4*)(E + j * KDIM + c0);
    uint4 ul = *(const uint4*)(L + j * KDIM + c0);
    float e[8], lp[8];
    bf8_to_f32(ue, e); bf8_to_f32(ul, lp);
    float dot = 0.0f, part = 0.0f;
    #pragma unroll
    for (int q = 0; q < 8; ++q) { float w = e[q] * a[q]; dot += w; part += w * lp[q]; }
    #pragma unroll
    for (int m = 1; m < 64; m <<= 1) dot += __shfl_xor(dot, m);
    #pragma unroll
    for (int m = 1; m < 64; m <<= 1) part += __shfl_xor(part, m);
    wsum += part / dot;
  }
  __shared__ float ws[4];
  if (lane == 0) ws[wid] = wsum;
  __syncthreads();
  if (tid == 0) {
    float tot = ws[0] + ws[1] + ws[2] + ws[3];
    atomicAdd(out, -tot * (1.0f / (float)B_ROWS));
  }
}

// ---------------- launcher ----------------
extern "C" void kernel_launch(void* const* d_in, const int* in_sizes, int n_in,
                              void* d_out, int out_size, void* d_ws, size_t ws_size,
                              hipStream_t stream) {
  const float* s  = (const float*)d_in[0];
  const float* t  = (const float*)d_in[1];
  const float* Wn = (const float*)d_in[2];
  const float* Wp = (const float*)d_in[3];
  float* out = (float*)d_out;

  char* w = (char*)d_ws;
  __hip_bfloat16* wnb = (__hip_bfloat16*)w; w += (size_t)KDIM * DDIM * 2;   // 1 MB
  __hip_bfloat16* cnb = (__hip_bfloat16*)w; w += (size_t)KDIM * KDIM * 2;   // 0.5 MB
  __hip_bfloat16* znb = (__hip_bfloat16*)w; w += (size_t)B_ROWS * KDIM * 2; // 32 MB
  __hip_bfloat16* lgp = (__hip_bfloat16*)w; w += (size_t)B_ROWS * KDIM * 2; // 32 MB
  __hip_bfloat16* ebf = (__hip_bfloat16*)w; w += (size_t)B_ROWS * KDIM * 2; // 32 MB
  float* small = (float*)w;
  float* csA = small;
  float* csB = small + 512;
  float* csC = small + 1024;

  zero_small<<<6, 256, 0, stream>>>(small, 1536, out);
  cvt_bf16<<<KDIM * DDIM / 8 / 256, 256, 0, stream>>>(Wn, wnb, KDIM * DDIM / 8);
  cn_norm<<<KDIM, 256, 0, stream>>>(Wp, cnb);

  // student: Zn(s) -> logp
  gemm_ns<<<B_ROWS / 128, 512, 0, stream>>>(s, wnb, znb);
  gemm_sc<0><<<B_ROWS / 128, 512, 0, stream>>>(znb, cnb, lgp, nullptr);
  // teacher: Zn(t) -> E + colsum
  gemm_ns<<<B_ROWS / 128, 512, 0, stream>>>(t, wnb, znb);
  gemm_sc<1><<<B_ROWS / 128, 512, 0, stream>>>(znb, cnb, ebf, csA);

  sink_iter<<<B_ROWS / 64, 256, 0, stream>>>(ebf, csA, csB);
  sink_iter<<<B_ROWS / 64, 256, 0, stream>>>(ebf, csB, csC);
  sink_final<<<B_ROWS / 64, 256, 0, stream>>>(ebf, csC, lgp, out);
}